// Round 2
// baseline (148.599 us; speedup 1.0000x reference)
//
#include <hip/hip_runtime.h>

// MPS tensor-train classifier, B=16384, D=784, BOND=5, OUT=10.
//
// Round-5: the kernel is LDS-issue-throughput bound (10,920 broadcast
// ds_read_b128 per CU ~= 131k cyc > whole-kernel 113k cyc; VALUBusy 37%,
// 0 bank conflicts, 17% HBM, insensitive to VGPR budget). Fix: 2 rows
// per lane so each broadcast pk read feeds TWO build_C's -> LDS instrs
// per row halved. 128 rows/block forces chain split: blockIdx = {group g,
// half h}. h=0: carry0+site0 + pairs 0..194 -> row-vector vL, stashed in
// out[row][0:5]. h=1: pairs 195..389 + site781+vlast -> col-vector wR in
// out[row][5:10]. Tiny finish kernel: out = (vL.wR)*fc_w + fc_b.
// Blocks: 512 thr = 8 waves (2/SIMD -> 256 VGPR budget for dual-row
// M,T,C state). Per half: 1 vector wave (41 pairs) + 7 matrix waves
// (22 pairs each); combine via matbuf after ONE barrier.
// pk repacked: 100 floats/pair, c44 quad contiguous -> 25 ds_read_b128
// per pair (was 28), staging -11%.

typedef float v4f __attribute__((ext_vector_type(4)));
typedef float v2f __attribute__((ext_vector_type(2)));

constexpr int Bn     = 16384;
constexpr int Dn     = 784;
constexpr int NOUT   = 10;
constexpr int NPAIR  = 390;   // pairs cover sites 1..780
constexpr int PVEC   = 41;    // pairs per vector wave (both halves)
constexpr int PMAT   = 22;    // pairs per matrix wave (7 waves per half)
constexpr int RHP0   = 195;   // right half first pair
constexpr int BWD_P0 = 349;   // bwd pairs 349..389 (stored transposed)
constexpr int PAIR_F = 100;   // floats per pair block: 4 mats x 25
constexpr int PAIR_V = 25;    // v4f per pair block
// per-pair layout (100 floats), q = 0..3 (1, xa, xb, xa*xb coefficient):
//   rows:  q*20 + l*4 + r   (l=0..4, r=0..3)
//   col4:  80 + q*4 + l     (l=0..3)
//   (4,4): 96 + q           (all four c44 in ONE v4f -> 1 read)

__device__ __forceinline__ v4f splat4(float x) { v4f v = {x, x, x, x}; return v; }
__device__ __forceinline__ v4f fma4(v4f a, v4f b, v4f c) {
    return __builtin_elementwise_fma(a, b, c);
}

struct Frag { v4f r[5]; float c4[5]; };          // 5x5 running product
struct CMat { v4f row[5]; v4f c4v; float c44; }; // 5x5 pair matrix

// build C for TWO rows from ONE pass over the pair block (25 ds_read_b128)
__device__ __forceinline__ void build_C2(const float* s, v2f xA, v2f xB,
                                         CMat& CA, CMat& CB) {
    const float aA = xA[0], bA = xA[1], pA = aA * bA;
    const float aB = xB[0], bB = xB[1], pB = aB * bB;
    const v4f vaA = splat4(aA), vbA = splat4(bA), vpA = splat4(pA);
    const v4f vaB = splat4(aB), vbB = splat4(bB), vpB = splat4(pB);
    const v4f* s4 = (const v4f*)s;
#pragma unroll
    for (int l = 0; l < 5; ++l) {
        v4f q0 = s4[l], q1 = s4[5 + l], q2 = s4[10 + l], q3 = s4[15 + l];
        CA.row[l] = fma4(vpA, q3, fma4(vbA, q2, fma4(vaA, q1, q0)));
        CB.row[l] = fma4(vpB, q3, fma4(vbB, q2, fma4(vaB, q1, q0)));
    }
    {
        v4f q0 = s4[20], q1 = s4[21], q2 = s4[22], q3 = s4[23];
        CA.c4v = fma4(vpA, q3, fma4(vbA, q2, fma4(vaA, q1, q0)));
        CB.c4v = fma4(vpB, q3, fma4(vbB, q2, fma4(vaB, q1, q0)));
    }
    {
        v4f q = s4[24];   // {c44 of q0, q1, q2, q3}
        CA.c44 = fmaf(pA, q[3], fmaf(bA, q[2], fmaf(aA, q[1], q[0])));
        CB.c44 = fmaf(pB, q[3], fmaf(bB, q[2], fmaf(aB, q[1], q[0])));
    }
}

// T = M @ C
__device__ __forceinline__ void matmul(const Frag& M, const CMat& C, Frag& T) {
#pragma unroll
    for (int i = 0; i < 5; ++i) {
        v4f acc  = splat4(M.r[i][0]) * C.row[0];
        float a4 = M.r[i][0] * C.c4v[0];
#pragma unroll
        for (int l = 1; l < 4; ++l) {
            acc = fma4(splat4(M.r[i][l]), C.row[l], acc);
            a4  = fmaf(M.r[i][l], C.c4v[l], a4);
        }
        acc = fma4(splat4(M.c4[i]), C.row[4], acc);
        a4  = fmaf(M.c4[i], C.c44, a4);
        T.r[i] = acc; T.c4[i] = a4;
    }
}

// c' = c @ C   (row vector)
__device__ __forceinline__ void vecstep(v4f& cv, float& c4, const CMat& C) {
    v4f acc  = splat4(cv[0]) * C.row[0];
    float a4 = cv[0] * C.c4v[0];
#pragma unroll
    for (int l = 1; l < 4; ++l) {
        acc = fma4(splat4(cv[l]), C.row[l], acc);
        a4  = fmaf(cv[l], C.c4v[l], a4);
    }
    acc = fma4(splat4(c4), C.row[4], acc);
    a4  = fmaf(c4, C.c44, a4);
    cv = acc; c4 = a4;
}

// staging: one chunk = 4 pair blocks = 100 v4f = 1600 B
__device__ __forceinline__ void sload(const v4f* src, v4f& a, v4f& b, int lane) {
    a = src[lane];
    if (lane < 36) b = src[64 + lane];
}
__device__ __forceinline__ void swrite(v4f* dst, v4f a, v4f b, int lane) {
    dst[lane] = a;
    if (lane < 36) dst[64 + lane] = b;
}

// ---- prepack: build pair blocks (transposed for p >= BWD_P0) ----
// cores_mid element (m,l,i,k) at (m*5+l)*10 + i*5 + k
__global__ void prepack_pairs(const float* __restrict__ cm, float* __restrict__ pk)
{
    int idx = blockIdx.x * 256 + threadIdx.x;
    if (idx >= NPAIR * 100) return;
    int p = idx / 100, rest = idx - p * 100;
    int q = rest / 25, e = rest - q * 25;
    int l = e / 5, r = e - l * 5;
    int m1 = 2 * p + 1, m2 = 2 * p + 2;
    const float* L = cm + (size_t)(m1 * 5 + l) * 10;
    float acc = 0.f;
#pragma unroll
    for (int k = 0; k < 5; ++k) {
        float Lk = (q & 1) ? (L[5 + k] - L[k]) : L[k];
        const float* R = cm + (size_t)(m2 * 5 + k) * 10;
        float Rk = (q & 2) ? (R[5 + r] - R[r]) : R[r];
        acc = fmaf(Lk, Rk, acc);
    }
    int wl = l, wr = r;
    if (p >= BWD_P0) { wl = r; wr = l; }   // store C^T for bwd wave
    int off;
    if (wr < 4)      off = q * 20 + wl * 4 + wr;
    else if (wl < 4) off = 80 + q * 4 + wl;
    else             off = 96 + q;
    pk[(size_t)p * PAIR_F + off] = acc;
}

__global__ __launch_bounds__(512, 2)
void mps_half_kernel(const float* __restrict__ x,          // [B, D]
                     const float* __restrict__ core_first, // [2,5]
                     const float* __restrict__ cores_mid,  // [782,5,2,5]
                     const float* __restrict__ core_last,  // [5,2]
                     const float* __restrict__ pk,         // [390][100]
                     float* __restrict__ out)              // [B,10] (stash)
{
    __shared__ v4f   pkbuf[8][2][100];    // 25.6 KB double-buffered chunks
    __shared__ float matbuf[7][25][128];  // 89.6 KB combine matrices

    const int lane = threadIdx.x & 63;
    const int wave = threadIdx.x >> 6;    // 0..7
    const int g    = blockIdx.x >> 1;
    const int h    = blockIdx.x & 1;
    const int rowA = g * 128 + lane;
    const int rowB = rowA + 64;
    const v2f* __restrict__ xA2 = (const v2f*)(x + (size_t)rowA * Dn);
    const v2f* __restrict__ xB2 = (const v2f*)(x + (size_t)rowB * Dn);
    const v4f* __restrict__ pk4 = (const v4f*)pk;

    v4f* buf0 = &pkbuf[wave][0][0];
    v4f* buf1 = &pkbuf[wave][1][0];

    const bool isvec = (h == 0) ? (wave == 0) : (wave == 7);

    if (!isvec) {
        // ---- matrix wave: 22 pairs, 6 chunks (5x4 + 1x2), 2 rows/lane ----
        const int slot = (h == 0) ? (wave - 1) : wave;
        const int p0   = (h == 0) ? (PVEC + PMAT * (wave - 1))
                                  : (RHP0 + PMAT * wave);
        v4f sa, sb;
        sload(pk4 + (size_t)p0 * PAIR_V, sa, sb, lane);
        swrite(buf0, sa, sb, lane);
        sload(pk4 + (size_t)(p0 + 4) * PAIR_V, sa, sb, lane);
        v2f cA0 = xA2[p0 + 1], cA1 = xA2[p0 + 2], cA2 = xA2[p0 + 3], cA3 = xA2[p0 + 4];
        v2f cB0 = xB2[p0 + 1], cB1 = xB2[p0 + 2], cB2 = xB2[p0 + 3], cB3 = xB2[p0 + 4];

        Frag MA, TA, MB, TB;
        MA.r[0] = {1,0,0,0}; MA.r[1] = {0,1,0,0}; MA.r[2] = {0,0,1,0};
        MA.r[3] = {0,0,0,1}; MA.r[4] = {0,0,0,0};
        MA.c4[0] = 0; MA.c4[1] = 0; MA.c4[2] = 0; MA.c4[3] = 0; MA.c4[4] = 1;
        MB = MA;

#pragma unroll 1
        for (int c = 0; c < 6; ++c) {
            v4f* wb = (c & 1) ? buf0 : buf1;
            const float* rb = (const float*)((c & 1) ? buf1 : buf0);
            swrite(wb, sa, sb, lane);                      // chunk c+1 -> LDS
            int ns = p0 + 4 * (c + 2);                     // next-next chunk
            if (ns > NPAIR - 4) ns = NPAIR - 4;
            sload(pk4 + (size_t)ns * PAIR_V, sa, sb, lane);
            const int pn = p0 + 4 * (c + 1);               // x prefetch
            v2f nA0 = xA2[pn + 1], nA1 = xA2[pn + 2], nA2 = xA2[pn + 3], nA3 = xA2[pn + 4];
            v2f nB0 = xB2[pn + 1], nB1 = xB2[pn + 2], nB2 = xB2[pn + 3], nB3 = xB2[pn + 4];
            CMat CA, CB;
            build_C2(rb + 0 * PAIR_F, cA0, cB0, CA, CB);
            matmul(MA, CA, TA); matmul(MB, CB, TB);
            build_C2(rb + 1 * PAIR_F, cA1, cB1, CA, CB);
            matmul(TA, CA, MA); matmul(TB, CB, MB);
            if (c < 5) {
                build_C2(rb + 2 * PAIR_F, cA2, cB2, CA, CB);
                matmul(MA, CA, TA); matmul(MB, CB, TB);
                build_C2(rb + 3 * PAIR_F, cA3, cB3, CA, CB);
                matmul(TA, CA, MA); matmul(TB, CB, MB);
            }
            cA0 = nA0; cA1 = nA1; cA2 = nA2; cA3 = nA3;
            cB0 = nB0; cB1 = nB1; cB2 = nB2; cB3 = nB3;
        }

#pragma unroll
        for (int i = 0; i < 5; ++i) {
#pragma unroll
            for (int r = 0; r < 4; ++r) {
                matbuf[slot][i * 5 + r][lane]      = MA.r[i][r];
                matbuf[slot][i * 5 + r][lane + 64] = MB.r[i][r];
            }
            matbuf[slot][i * 5 + 4][lane]      = MA.c4[i];
            matbuf[slot][i * 5 + 4][lane + 64] = MB.c4[i];
        }
        __syncthreads();
    } else if (h == 0) {
        // ---- left vector wave: carry0, site 0, pairs 0..40, combine ----
        v2f xA01 = xA2[0], xB01 = xB2[0];
        float clA[5], clB[5], cnA[5], cnB[5];
#pragma unroll
        for (int r = 0; r < 5; ++r) {
            float d = core_first[5 + r] - core_first[r];
            clA[r] = fmaf(xA01[0], d, core_first[r]);
            clB[r] = fmaf(xB01[0], d, core_first[r]);
        }
        const float* cm0 = cores_mid;                      // site 0
#pragma unroll
        for (int r = 0; r < 5; ++r) {
            float aA = 0.f, aB = 0.f;
#pragma unroll
            for (int l = 0; l < 5; ++l) {
                float base = cm0[l * 10 + r], d = cm0[l * 10 + 5 + r] - base;
                aA = fmaf(clA[l], fmaf(xA01[1], d, base), aA);
                aB = fmaf(clB[l], fmaf(xB01[1], d, base), aB);
            }
            cnA[r] = aA; cnB[r] = aB;
        }
        v4f cvA = {cnA[0], cnA[1], cnA[2], cnA[3]};
        v4f cvB = {cnB[0], cnB[1], cnB[2], cnB[3]};
        float c4A = cnA[4], c4B = cnB[4];

        v4f sa, sb;
        sload(pk4 + 0, sa, sb, lane);
        swrite(buf0, sa, sb, lane);
        sload(pk4 + (size_t)4 * PAIR_V, sa, sb, lane);
        v2f cA0 = xA2[1], cA1 = xA2[2], cA2 = xA2[3], cA3 = xA2[4];
        v2f cB0 = xB2[1], cB1 = xB2[2], cB2 = xB2[3], cB3 = xB2[4];

#pragma unroll 1
        for (int c = 0; c < 11; ++c) {                     // 10x4 + 1x1 = 41 pairs
            v4f* wb = (c & 1) ? buf0 : buf1;
            const float* rb = (const float*)((c & 1) ? buf1 : buf0);
            swrite(wb, sa, sb, lane);
            int ns = 4 * (c + 2);
            if (ns > NPAIR - 4) ns = NPAIR - 4;
            sload(pk4 + (size_t)ns * PAIR_V, sa, sb, lane);
            const int pn = 4 * (c + 1);
            v2f nA0 = xA2[pn + 1], nA1 = xA2[pn + 2], nA2 = xA2[pn + 3], nA3 = xA2[pn + 4];
            v2f nB0 = xB2[pn + 1], nB1 = xB2[pn + 2], nB2 = xB2[pn + 3], nB3 = xB2[pn + 4];
            CMat CA, CB;
            build_C2(rb + 0 * PAIR_F, cA0, cB0, CA, CB);
            vecstep(cvA, c4A, CA); vecstep(cvB, c4B, CB);
            if (c < 10) {
                build_C2(rb + 1 * PAIR_F, cA1, cB1, CA, CB);
                vecstep(cvA, c4A, CA); vecstep(cvB, c4B, CB);
                build_C2(rb + 2 * PAIR_F, cA2, cB2, CA, CB);
                vecstep(cvA, c4A, CA); vecstep(cvB, c4B, CB);
                build_C2(rb + 3 * PAIR_F, cA3, cB3, CA, CB);
                vecstep(cvA, c4A, CA); vecstep(cvB, c4B, CB);
            }
            cA0 = nA0; cA1 = nA1; cA2 = nA2; cA3 = nA3;
            cB0 = nB0; cB1 = nB1; cB2 = nB2; cB3 = nB3;
        }
        clA[0] = cvA[0]; clA[1] = cvA[1]; clA[2] = cvA[2]; clA[3] = cvA[3]; clA[4] = c4A;
        clB[0] = cvB[0]; clB[1] = cvB[1]; clB[2] = cvB[2]; clB[3] = cvB[3]; clB[4] = c4B;

        __syncthreads();   // matrix waves' matbuf ready
#pragma unroll 1
        for (int w2 = 0; w2 < 7; ++w2) {
            float vA[5], vB[5];
#pragma unroll
            for (int r = 0; r < 5; ++r) {
                vA[r] = clA[0] * matbuf[w2][r][lane];
                vB[r] = clB[0] * matbuf[w2][r][lane + 64];
            }
#pragma unroll
            for (int l = 1; l < 5; ++l)
#pragma unroll
                for (int r = 0; r < 5; ++r) {
                    vA[r] = fmaf(clA[l], matbuf[w2][l * 5 + r][lane],      vA[r]);
                    vB[r] = fmaf(clB[l], matbuf[w2][l * 5 + r][lane + 64], vB[r]);
                }
#pragma unroll
            for (int r = 0; r < 5; ++r) { clA[r] = vA[r]; clB[r] = vB[r]; }
        }
        float* oA = out + (size_t)rowA * NOUT;
        float* oB = out + (size_t)rowB * NOUT;
#pragma unroll
        for (int i = 0; i < 5; ++i) { oA[i] = clA[i]; oB[i] = clB[i]; }
    } else {
        // ---- right vector wave: vlast, site 781, pairs 389..349 desc,
        //      combine down through matrix slots 6..0 ----
        v2f xAz = xA2[391], xBz = xB2[391];                // {x782, x783}
        float vlA[5], vlB[5], vnA[5], vnB[5];
#pragma unroll
        for (int l = 0; l < 5; ++l) {
            float base = core_last[2 * l], d = core_last[2 * l + 1] - base;
            vlA[l] = fmaf(xAz[1], d, base);
            vlB[l] = fmaf(xBz[1], d, base);
        }
        const float* cmL = cores_mid + (size_t)781 * 50;
#pragma unroll
        for (int l = 0; l < 5; ++l) {
            float aA = 0.f, aB = 0.f;
#pragma unroll
            for (int r = 0; r < 5; ++r) {
                float base = cmL[l * 10 + r], d = cmL[l * 10 + 5 + r] - base;
                aA = fmaf(fmaf(xAz[0], d, base), vlA[r], aA);
                aB = fmaf(fmaf(xBz[0], d, base), vlB[r], aB);
            }
            vnA[l] = aA; vnB[l] = aB;
        }
        v4f cvA = {vnA[0], vnA[1], vnA[2], vnA[3]};
        v4f cvB = {vnB[0], vnB[1], vnB[2], vnB[3]};
        float c4A = vnA[4], c4B = vnB[4];

        v4f sa, sb;
        sload(pk4 + (size_t)386 * PAIR_V, sa, sb, lane);   // chunk0: pairs 386..389
        swrite(buf0, sa, sb, lane);
        sload(pk4 + (size_t)382 * PAIR_V, sa, sb, lane);
        v2f cA0 = xA2[390], cA1 = xA2[389], cA2 = xA2[388], cA3 = xA2[387];
        v2f cB0 = xB2[390], cB1 = xB2[389], cB2 = xB2[388], cB3 = xB2[387];

#pragma unroll 1
        for (int c = 0; c < 11; ++c) {                     // 10x4 + 1x1 = 41 pairs
            v4f* wb = (c & 1) ? buf0 : buf1;
            const float* rb = (const float*)((c & 1) ? buf1 : buf0);
            swrite(wb, sa, sb, lane);
            int ns = 386 - 4 * (c + 2);                    // >= 338, in bounds
            sload(pk4 + (size_t)ns * PAIR_V, sa, sb, lane);
            const int bn = 386 - 4 * (c + 1);
            v2f nA0 = xA2[bn + 4], nA1 = xA2[bn + 3], nA2 = xA2[bn + 2], nA3 = xA2[bn + 1];
            v2f nB0 = xB2[bn + 4], nB1 = xB2[bn + 3], nB2 = xB2[bn + 2], nB3 = xB2[bn + 1];
            CMat CA, CB;
            build_C2(rb + 3 * PAIR_F, cA0, cB0, CA, CB);   // highest pair first
            vecstep(cvA, c4A, CA); vecstep(cvB, c4B, CB);
            if (c < 10) {
                build_C2(rb + 2 * PAIR_F, cA1, cB1, CA, CB);
                vecstep(cvA, c4A, CA); vecstep(cvB, c4B, CB);
                build_C2(rb + 1 * PAIR_F, cA2, cB2, CA, CB);
                vecstep(cvA, c4A, CA); vecstep(cvB, c4B, CB);
                build_C2(rb + 0 * PAIR_F, cA3, cB3, CA, CB);
                vecstep(cvA, c4A, CA); vecstep(cvB, c4B, CB);
            }
            cA0 = nA0; cA1 = nA1; cA2 = nA2; cA3 = nA3;
            cB0 = nB0; cB1 = nB1; cB2 = nB2; cB3 = nB3;
        }
        float uA[5] = {cvA[0], cvA[1], cvA[2], cvA[3], c4A};
        float uB[5] = {cvB[0], cvB[1], cvB[2], cvB[3], c4B};

        __syncthreads();   // matrix waves' matbuf ready
#pragma unroll 1
        for (int w2 = 6; w2 >= 0; --w2) {                  // u = M_slot @ u
            float vA[5], vB[5];
#pragma unroll
            for (int i = 0; i < 5; ++i) {
                float aA = matbuf[w2][i * 5][lane]      * uA[0];
                float aB = matbuf[w2][i * 5][lane + 64] * uB[0];
#pragma unroll
                for (int l = 1; l < 5; ++l) {
                    aA = fmaf(matbuf[w2][i * 5 + l][lane],      uA[l], aA);
                    aB = fmaf(matbuf[w2][i * 5 + l][lane + 64], uB[l], aB);
                }
                vA[i] = aA; vB[i] = aB;
            }
#pragma unroll
            for (int i = 0; i < 5; ++i) { uA[i] = vA[i]; uB[i] = vB[i]; }
        }
        float* oA = out + (size_t)rowA * NOUT;
        float* oB = out + (size_t)rowB * NOUT;
#pragma unroll
        for (int i = 0; i < 5; ++i) { oA[5 + i] = uA[i]; oB[5 + i] = uB[i]; }
    }
}

// ---- stage 2: res = vL . wR ; out = res*fc_w + fc_b ----
__global__ __launch_bounds__(256)
void finish_out(const float* __restrict__ fc_w, const float* __restrict__ fc_b,
                float* __restrict__ out)
{
    int row = blockIdx.x * 256 + threadIdx.x;
    float* o = out + (size_t)row * NOUT;
    v2f e0 = *(const v2f*)(o + 0);
    v2f e1 = *(const v2f*)(o + 2);
    v2f e2 = *(const v2f*)(o + 4);
    v2f e3 = *(const v2f*)(o + 6);
    v2f e4 = *(const v2f*)(o + 8);
    float res = e0[0] * e2[1];
    res = fmaf(e0[1], e3[0], res);
    res = fmaf(e1[0], e3[1], res);
    res = fmaf(e1[1], e4[0], res);
    res = fmaf(e2[0], e4[1], res);
#pragma unroll
    for (int j = 0; j < NOUT; ++j) o[j] = fmaf(res, fc_w[j], fc_b[j]);
}

extern "C" void kernel_launch(void* const* d_in, const int* in_sizes, int n_in,
                              void* d_out, int out_size, void* d_ws, size_t ws_size,
                              hipStream_t stream) {
    const float* x          = (const float*)d_in[0];
    const float* core_first = (const float*)d_in[1];
    const float* cores_mid  = (const float*)d_in[2];
    const float* core_last  = (const float*)d_in[3];
    const float* fc_w       = (const float*)d_in[4];
    const float* fc_b       = (const float*)d_in[5];
    float* out              = (float*)d_out;
    float* pk               = (float*)d_ws;   // 390*100*4 = 156,000 B

    hipLaunchKernelGGL(prepack_pairs, dim3((NPAIR * 100 + 255) / 256), dim3(256),
                       0, stream, cores_mid, pk);
    hipLaunchKernelGGL(mps_half_kernel, dim3(256), dim3(512), 0, stream,
                       x, core_first, cores_mid, core_last, pk, out);
    hipLaunchKernelGGL(finish_out, dim3(Bn / 256), dim3(256), 0, stream,
                       fc_w, fc_b, out);
}